// Round 3
// baseline (105.509 us; speedup 1.0000x reference)
//
#include <hip/hip_runtime.h>
#include <cstdint>
#include <cstddef>

#define Bsz 8
#define Ssz 256
#define Msz (Bsz*Ssz)   // 2048

typedef _Float16 f16x8 __attribute__((ext_vector_type(8)));
typedef _Float16 f16x4 __attribute__((ext_vector_type(4)));
typedef float f32x4 __attribute__((ext_vector_type(4)));

// ---------- fused fp32->fp16 casts: W_dep, W_comp, dep ----------
__global__ void k_cvt3(const float* __restrict__ a, int na4,
                       const float* __restrict__ b, int nb4,
                       const float* __restrict__ c,
                       _Float16* __restrict__ oa, _Float16* __restrict__ ob,
                       _Float16* __restrict__ oc) {
  int i = blockIdx.x * 256 + threadIdx.x;
  const float4* src; f16x4* dst; int off;
  if (i < na4)            { src = (const float4*)a; dst = (f16x4*)oa; off = i; }
  else if (i < na4 + nb4) { src = (const float4*)b; dst = (f16x4*)ob; off = i - na4; }
  else                    { src = (const float4*)c; dst = (f16x4*)oc; off = i - na4 - nb4; }
  float4 v = src[off];
  f16x4 o = {(_Float16)v.x, (_Float16)v.y, (_Float16)v.z, (_Float16)v.w};
  dst[off] = o;
}

// ---------- phase GEMM + fused t-contraction epilogue ----------
// Block (x=m-block, y=p or o). MFMA dims: M=t(128 rows), N=m(128 cols), K=64|128.
// A[row=t][k] = W[(y*128+t)*K + k]  (native layout, contiguous)
// B[col=m][k] = Bv[(m0+m)*K + k]    (dep_h or h, contiguous)
// C[t][m] in frags; epilogue: out[m][y] = tanh(sum_t tok[m,t]*C[t][m] + bias[y])
template<int K, bool OUT_HALF>
__global__ __launch_bounds__(256) void k_phase(
    const _Float16* __restrict__ W,
    const _Float16* __restrict__ Bv,
    const float*    __restrict__ tok,   // [Msz][128] fp32
    const float*    __restrict__ bias,
    void*           __restrict__ outp)  // [Msz][128] fp16 or fp32
{
  __shared__ float red[2][128];
  const int tid  = threadIdx.x;
  const int lane = tid & 63;
  const int wave = tid >> 6;
  const int wt = wave >> 1;           // t-half (MFMA M)
  const int wm = wave & 1;            // m-half (MFMA N)
  const int l15 = lane & 15;
  const int lg  = (lane >> 4) & 3;
  const int m0  = blockIdx.x * 128;
  const int y   = blockIdx.y;

  f32x4 acc[4][4];
  #pragma unroll
  for (int i = 0; i < 4; i++)
    #pragma unroll
    for (int j = 0; j < 4; j++) acc[i][j] = (f32x4){0.f, 0.f, 0.f, 0.f};

  const _Float16* Wt = W + (size_t)y * 128 * K;

  #pragma unroll
  for (int kf = 0; kf < K / 32; ++kf) {
    f16x8 af[4], bf[4];
    #pragma unroll
    for (int mfi = 0; mfi < 4; mfi++)
      af[mfi] = *reinterpret_cast<const f16x8*>(
          &Wt[(size_t)(wt * 64 + mfi * 16 + l15) * K + kf * 32 + lg * 8]);
    #pragma unroll
    for (int nfi = 0; nfi < 4; nfi++)
      bf[nfi] = *reinterpret_cast<const f16x8*>(
          &Bv[(size_t)(m0 + wm * 64 + nfi * 16 + l15) * K + kf * 32 + lg * 8]);
    #pragma unroll
    for (int mfi = 0; mfi < 4; mfi++)
      #pragma unroll
      for (int nfi = 0; nfi < 4; nfi++)
        acc[mfi][nfi] = __builtin_amdgcn_mfma_f32_16x16x32_f16(af[mfi], bf[nfi], acc[mfi][nfi], 0, 0, 0);
  }

  // epilogue: per acc elem, row t = wt*64+mfi*16+lg*4+r, col m = wm*64+nfi*16+l15
  #pragma unroll
  for (int nfi = 0; nfi < 4; nfi++) {
    const int mcol = m0 + wm * 64 + nfi * 16 + l15;
    float s = 0.f;
    #pragma unroll
    for (int mfi = 0; mfi < 4; mfi++) {
      float4 tk = *reinterpret_cast<const float4*>(
          &tok[(size_t)mcol * 128 + wt * 64 + mfi * 16 + lg * 4]);
      s += tk.x * acc[mfi][nfi][0] + tk.y * acc[mfi][nfi][1]
         + tk.z * acc[mfi][nfi][2] + tk.w * acc[mfi][nfi][3];
    }
    s += __shfl_xor(s, 16);   // combine lg groups (rows lg*4..)
    s += __shfl_xor(s, 32);
    if (lane < 16) red[wt][wm * 64 + nfi * 16 + lane] = s;
  }
  __syncthreads();
  if (tid < 128) {
    float v = red[0][tid] + red[1][tid] + bias[y];
    float t = tanhf(v);
    if (OUT_HALF) ((_Float16*)outp)[(size_t)(m0 + tid) * 128 + y] = (_Float16)t;
    else          ((float*)   outp)[(size_t)(m0 + tid) * 128 + y] = t;
  }
}

// ---------- epilogue: gather over j with head[b,j]==i ----------
__global__ __launch_bounds__(128) void k_finalize(
    const float* __restrict__ special,  // [Msz][128] fp32
    const int*   __restrict__ heads,    // [Bsz][Ssz]
    const float* __restrict__ wred,     // [Ssz]
    const float* __restrict__ bred,     // [1]
    const float* __restrict__ bcomp,    // [128]
    float* __restrict__ out)            // [Bsz][Ssz][128]
{
  int b = blockIdx.x >> 8;
  int i = blockIdx.x & 255;
  int t = threadIdx.x;
  __shared__ float wr_s[Ssz];
  __shared__ int   hd_s[Ssz];
  wr_s[t]       = wred[t];
  wr_s[t + 128] = wred[t + 128];
  hd_s[t]       = heads[b * Ssz + t];
  hd_s[t + 128] = heads[b * Ssz + t + 128];
  __syncthreads();

  float base = tanhf(bcomp[t]);
  float swr = 0.f, accv = 0.f;
  for (int j = 0; j < Ssz; j++) {
    swr += wr_s[j];
    if (hd_s[j] == i)
      accv += wr_s[j] * (special[((size_t)b * Ssz + j) * 128 + t] - base);
  }
  out[((size_t)b * Ssz + i) * 128 + t] = base * swr + bred[0] + accv;
}

extern "C" void kernel_launch(void* const* d_in, const int* in_sizes, int n_in,
                              void* d_out, int out_size, void* d_ws, size_t ws_size,
                              hipStream_t stream) {
  const float* tok   = (const float*)d_in[0];
  const float* dep   = (const float*)d_in[1];
  const int*   hds   = (const int*)  d_in[2];
  const float* Wdep  = (const float*)d_in[3];
  const float* bdep  = (const float*)d_in[4];
  const float* Wcomp = (const float*)d_in[5];
  const float* bcomp = (const float*)d_in[6];
  const float* Wred  = (const float*)d_in[7];
  const float* bred  = (const float*)d_in[8];
  float* out = (float*)d_out;

  char* ws = (char*)d_ws;
  _Float16* W1h  = (_Float16*)(ws);                    // 128*8192  f16 = 2 MB
  _Float16* W2h  = (_Float16*)(ws + (2u << 20));       // 128*16384 f16 = 4 MB
  _Float16* deph = (_Float16*)(ws + (6u << 20));       // 2048*64   f16 = 256 KB
  _Float16* h    = (_Float16*)(ws + (6u << 20) + (256u << 10));  // 2048*128 f16 = 512 KB
  float*    spc  = (float*)   (ws + (7u << 20));       // 2048*128  f32 = 1 MB

  // casts: Wdep 262144 f4, Wcomp 524288 f4, dep 32768 f4 -> 3200 blocks
  k_cvt3<<<3200, 256, 0, stream>>>(Wdep, 262144, Wcomp, 524288, dep, W1h, W2h, deph);

  // Phase 1: per (m-block, p): G = W1[p]·dep^T (K=64), contract t with tok -> h fp16
  k_phase<64,  true ><<<dim3(Msz / 128, 128), 256, 0, stream>>>(W1h, deph, tok, bdep,  (void*)h);
  // Phase 2: per (m-block, o): F = W2[o]·h^T (K=128), contract t with tok -> spc fp32
  k_phase<128, false><<<dim3(Msz / 128, 128), 256, 0, stream>>>(W2h, h,    tok, bcomp, (void*)spc);

  k_finalize<<<dim3(Bsz * Ssz), 128, 0, stream>>>(spc, hds, Wred, bred, bcomp, out);
}

// Round 4
// 59.283 us; speedup vs baseline: 1.7798x; 1.7798x over previous
//
#include <hip/hip_runtime.h>
#include <cstdint>
#include <cstddef>

#define Bsz 8
#define Ssz 256
#define Msz 2048
#define SPLITK 16

typedef _Float16 f16x8 __attribute__((ext_vector_type(8)));
typedef float f32x16 __attribute__((ext_vector_type(16)));

// ---------------- one-time pack kernel ----------------
// W1 [128][8192] f32  -> W1pk [512 kc][4 pb][64 lane][8] f16
// W2 [128][16384] f32 -> W2pk [1024][4][64][8] f16
// dep [2048][64] f32  -> dpk  [8 pc][2048 m][8] f16
// tok [2048][128] f32 -> tokT [128 t][2048 m] f16
__global__ __launch_bounds__(256) void k_pack(
    const float* __restrict__ W1, const float* __restrict__ W2,
    const float* __restrict__ dep, const float* __restrict__ tok,
    _Float16* __restrict__ W1pk, _Float16* __restrict__ W2pk,
    _Float16* __restrict__ dpk,  _Float16* __restrict__ tokT)
{
  __shared__ float tile[32][33];
  const int bx = blockIdx.x, tid = threadIdx.x;

  if (bx < 768) {            // W1 (bx<256) or W2
    const bool isW1 = bx < 256;
    const int idx = (isW1 ? bx : bx - 256) * 256 + tid;
    const int r  = idx & 31;
    const int pb = (idx >> 5) & 3;
    const int kc = idx >> 7;
    const float* src = (isW1 ? W1 : W2) + (size_t)(pb * 32 + r) * (isW1 ? 8192 : 16384) + kc * 16;
    const float4* s4 = (const float4*)src;
    float4 u0 = s4[0], u1 = s4[1], u2 = s4[2], u3 = s4[3];
    f16x8 lo = {(_Float16)u0.x,(_Float16)u0.y,(_Float16)u0.z,(_Float16)u0.w,
                (_Float16)u1.x,(_Float16)u1.y,(_Float16)u1.z,(_Float16)u1.w};
    f16x8 hi = {(_Float16)u2.x,(_Float16)u2.y,(_Float16)u2.z,(_Float16)u2.w,
                (_Float16)u3.x,(_Float16)u3.y,(_Float16)u3.z,(_Float16)u3.w};
    _Float16* dst = (isW1 ? W1pk : W2pk) + ((size_t)(kc * 4 + pb) * 64) * 8;
    *(f16x8*)(dst + (size_t)r * 8)        = lo;   // lane r      (k-chunk 0)
    *(f16x8*)(dst + (size_t)(32 + r) * 8) = hi;   // lane 32+r   (k-chunk 1)
  } else if (bx < 832) {     // dep pack
    const int idx = (bx - 768) * 256 + tid;
    const int m = idx & 2047, pc = idx >> 11;
    const float4* s4 = (const float4*)(dep + (size_t)m * 64 + pc * 8);
    float4 u0 = s4[0], u1 = s4[1];
    f16x8 v = {(_Float16)u0.x,(_Float16)u0.y,(_Float16)u0.z,(_Float16)u0.w,
               (_Float16)u1.x,(_Float16)u1.y,(_Float16)u1.z,(_Float16)u1.w};
    *(f16x8*)(dpk + ((size_t)pc * Msz + m) * 8) = v;
  } else {                   // tok transpose (32x32 tiles)
    const int q = bx - 832;              // 0..255
    const int mt = q >> 2, tt = q & 3;
    const int tx = tid & 31, ty = tid >> 5;
    for (int yy = ty; yy < 32; yy += 8)
      tile[yy][tx] = tok[(size_t)(mt * 32 + yy) * 128 + tt * 32 + tx];
    __syncthreads();
    for (int yy = ty; yy < 32; yy += 8)
      tokT[(size_t)(tt * 32 + yy) * Msz + mt * 32 + tx] = (_Float16)tile[tx][yy];
  }
}

// ---------------- MFMA GEMM, all operands pre-packed, no LDS ----------------
// C_part[sk][m][n] = sum_{k in chunk} (tok[m,t] * Apk[m, k&(DV-1)]) * W[n][k]
// k = t*DV + p.  mfma_f32_32x32x16_f16: A row=lane&31, k=(lane>>5)*8+j; B col likewise;
// D col=lane&31, row=(reg&3)+8*(reg>>2)+4*(lane>>5).
template<int LGDV, int KC>
__global__ __launch_bounds__(512, 2) void k_gemm(
    const _Float16* __restrict__ Apk,   // [DV/8][Msz][8]
    const _Float16* __restrict__ Wpk,   // [Ktot/16][4][64][8]
    const _Float16* __restrict__ tokT,  // [128][Msz]
    float* __restrict__ part)           // [SPLITK][Msz][128]
{
  constexpr int DV  = 1 << LGDV;
  constexpr int NT  = KC >> LGDV;      // t's per block (8)
  constexpr int NKS = DV >> 4;         // K-steps per t (4 or 8)

  const int tid  = threadIdx.x;
  const int lane = tid & 63;
  const int wv   = tid >> 6;           // 0..7
  const int wm   = wv >> 2;            // m-half (64 rows)
  const int wo   = wv & 3;             // o-quarter (32 cols)
  const int l31  = lane & 31;
  const int lg   = lane >> 5;
  const int m0   = blockIdx.x * 128;
  const int sk   = blockIdx.y;

  const int mA0   = m0 + wm * 64;
  const int mrow0 = mA0 + l31;

  f32x16 acc0 = {}, acc1 = {};

  const int t0 = sk * NT;
  #pragma unroll 1
  for (int tg = 0; tg < NT; ++tg) {
    const int t = t0 + tg;
    const _Float16 ta = tokT[(size_t)t * Msz + mrow0];
    const _Float16 tb = tokT[(size_t)t * Msz + mrow0 + 32];
    const f16x8 tav = {ta,ta,ta,ta,ta,ta,ta,ta};
    const f16x8 tbv = {tb,tb,tb,tb,tb,tb,tb,tb};
    const int kcBase = sk * (KC >> 4) + tg * NKS;
    #pragma unroll
    for (int ks = 0; ks < NKS; ++ks) {
      const f16x8 b = *(const f16x8*)(Wpk + (((size_t)(kcBase + ks) * 4 + wo) * 64 + lane) * 8);
      const _Float16* ap = Apk + ((size_t)(ks * 2 + lg) * Msz + mrow0) * 8;
      const f16x8 a0 = *(const f16x8*)(ap);
      const f16x8 a1 = *(const f16x8*)(ap + 32 * 8);
      const f16x8 af0 = tav * a0;
      const f16x8 af1 = tbv * a1;
      acc0 = __builtin_amdgcn_mfma_f32_32x32x16_f16(af0, b, acc0, 0, 0, 0);
      acc1 = __builtin_amdgcn_mfma_f32_32x32x16_f16(af1, b, acc1, 0, 0, 0);
    }
  }

  float* dst = part + (size_t)sk * Msz * 128;
  const int ocol = wo * 32 + l31;
  #pragma unroll
  for (int r = 0; r < 16; ++r) {
    const int mrow = mA0 + (r & 3) + 8 * (r >> 2) + 4 * lg;
    dst[(size_t)mrow * 128 + ocol]        = acc0[r];
    dst[(size_t)(mrow + 32) * 128 + ocol] = acc1[r];
  }
}

// ---------------- split-K reduce + bias + tanh ----------------
template<bool TO_HPK>
__global__ void k_red(const float* __restrict__ part, const float* __restrict__ bias,
                      _Float16* __restrict__ hpk, float* __restrict__ spc) {
  const int e = blockIdx.x * 256 + threadIdx.x;   // 262144 total
  const int m = e >> 7, p = e & 127;
  float s = bias[p];
  #pragma unroll
  for (int sk = 0; sk < SPLITK; sk++) s += part[(size_t)sk * (Msz * 128) + e];
  const float v = tanhf(s);
  if (TO_HPK) hpk[((size_t)(p >> 3) * Msz + m) * 8 + (p & 7)] = (_Float16)v;
  else        spc[e] = v;
}

// ---------------- epilogue: gather over j with head[b,j]==i ----------------
__global__ __launch_bounds__(128) void k_finalize(
    const float* __restrict__ special,  // [Msz][128]
    const int*   __restrict__ heads,    // [Bsz][Ssz]
    const float* __restrict__ wred,     // [Ssz]
    const float* __restrict__ bred,     // [1]
    const float* __restrict__ bcomp,    // [128]
    float* __restrict__ out)            // [Bsz][Ssz][128]
{
  int b = blockIdx.x >> 8;
  int i = blockIdx.x & 255;
  int t = threadIdx.x;
  __shared__ float wr_s[Ssz];
  __shared__ int   hd_s[Ssz];
  wr_s[t]       = wred[t];
  wr_s[t + 128] = wred[t + 128];
  hd_s[t]       = heads[b * Ssz + t];
  hd_s[t + 128] = heads[b * Ssz + t + 128];
  __syncthreads();

  float base = tanhf(bcomp[t]);
  float swr = 0.f, accv = 0.f;
  for (int j = 0; j < Ssz; j++) {
    swr += wr_s[j];
    if (hd_s[j] == i)
      accv += wr_s[j] * (special[((size_t)b * Ssz + j) * 128 + t] - base);
  }
  out[((size_t)b * Ssz + i) * 128 + t] = base * swr + bred[0] + accv;
}

extern "C" void kernel_launch(void* const* d_in, const int* in_sizes, int n_in,
                              void* d_out, int out_size, void* d_ws, size_t ws_size,
                              hipStream_t stream) {
  const float* tok   = (const float*)d_in[0];
  const float* dep   = (const float*)d_in[1];
  const int*   hds   = (const int*)  d_in[2];
  const float* Wdep  = (const float*)d_in[3];
  const float* bdep  = (const float*)d_in[4];
  const float* Wcomp = (const float*)d_in[5];
  const float* bcomp = (const float*)d_in[6];
  const float* Wred  = (const float*)d_in[7];
  const float* bred  = (const float*)d_in[8];
  float* out = (float*)d_out;

  char* ws = (char*)d_ws;
  _Float16* W1pk = (_Float16*)(ws);                 // 1,048,576 f16 = 2 MB
  _Float16* W2pk = (_Float16*)(ws + (2u  << 20));   // 2,097,152 f16 = 4 MB
  _Float16* dpk  = (_Float16*)(ws + (6u  << 20));   //   131,072 f16 = 256 KB
  _Float16* tokT = (_Float16*)(ws + (7u  << 20));   //   262,144 f16 = 512 KB
  _Float16* hpk  = (_Float16*)(ws + (8u  << 20));   //   262,144 f16 = 512 KB
  float*    part = (float*)   (ws + (9u  << 20));   // 16 MB (reused by both phases)
  float*    spc  = (float*)   (ws + (25u << 20));   // 1 MB

  k_pack<<<1088, 256, 0, stream>>>(Wdep, Wcomp, dep, tok, W1pk, W2pk, dpk, tokT);

  // Phase 1: tde. K=8192 (t*64+d). 16 m-blocks x 16 splitK, 512 thr.
  k_gemm<6, 512><<<dim3(16, SPLITK), 512, 0, stream>>>(dpk, W1pk, tokT, part);
  k_red<true><<<1024, 256, 0, stream>>>(part, bdep, hpk, nullptr);

  // Phase 2: composition. K=16384 (t*128+p).
  k_gemm<7, 1024><<<dim3(16, SPLITK), 512, 0, stream>>>(hpk, W2pk, tokT, part);
  k_red<false><<<1024, 256, 0, stream>>>(part, bcomp, nullptr, spc);

  k_finalize<<<dim3(Bsz * Ssz), 128, 0, stream>>>(spc, hds, Wred, bred, bcomp, out);
}